// Round 2
// baseline (7986.166 us; speedup 1.0000x reference)
//
#include <hip/hip_runtime.h>
#include <hip/hip_bf16.h>

typedef unsigned short u16;
typedef unsigned int u32;
typedef __attribute__((ext_vector_type(8))) short short8;
typedef __attribute__((ext_vector_type(4))) float f32x4;

// sizes: V=50000 E=256 H=512 T=50 C=5 B=128 S=512 FC1=500, 4H=2048
// ALL float tensors are f32 on device; x is int32; d_out is f32.

__device__ __forceinline__ float bf2f(u16 v){ union{u32 u; float f;} x; x.u = ((u32)v)<<16; return x.f; }
__device__ __forceinline__ u16 f2bf(float f){ union{float f; u32 u;} x; x.f = f; u32 r = ((x.u>>16)&1u) + 0x7FFFu; return (u16)((x.u + r)>>16); }
__device__ __forceinline__ float sigf(float x){ return 1.f/(1.f+__expf(-x)); }
__device__ __forceinline__ float tanh_f(float x){ return 2.f/(1.f+__expf(-2.f*x)) - 1.f; }

// ---- transpose+cast: W_h f32 [512][2048] -> WhT bf16 [2048][512]
//                      W_x f32 [256][2048] -> WxT bf16 [2048][256]
__global__ void k_prep(const float* __restrict__ Wh, const float* __restrict__ Wx,
                       u16* __restrict__ WhT, u16* __restrict__ WxT){
  __shared__ u16 tile[32][33];
  int b = blockIdx.x;
  const float* src; u16* dst; int K, kt, nt;
  if (b < 1024){ src = Wh; dst = WhT; K = 512; kt = b & 15; nt = b >> 4; }
  else { b -= 1024; src = Wx; dst = WxT; K = 256; kt = b & 7; nt = b >> 3; }
  int tx = threadIdx.x, ty = threadIdx.y;
  #pragma unroll
  for (int p = 0; p < 4; ++p){
    int r = p*8 + ty;
    tile[r][tx] = f2bf(src[(kt*32 + r)*2048 + nt*32 + tx]);
  }
  __syncthreads();
  #pragma unroll
  for (int p = 0; p < 4; ++p){
    int r = p*8 + ty;
    dst[(nt*32 + r)*K + kt*32 + tx] = tile[tx][r];
  }
}

// ---- tb[b][col] = bias[col] + sum_t topic[b][t]*W_t[t][col]   (all f32)
__global__ void k_topic(const float* __restrict__ topic, const float* __restrict__ Wt,
                        const float* __restrict__ bias, float* __restrict__ tb){
  int b = blockIdx.y;
  int col = blockIdx.x*256 + threadIdx.x;
  float acc = bias[col];
  #pragma unroll 5
  for (int t = 0; t < 50; ++t)
    acc += topic[b*50 + t] * Wt[t*2048 + col];
  tb[b*2048 + col] = acc;
}

// ---- init h ring buffer parity 0 (hi+lo split of f32 h0) and zero flag counters
__global__ void k_init(const float* __restrict__ h0, u16* __restrict__ hhi,
                       u16* __restrict__ hlo, u32* __restrict__ cnt){
  if (blockIdx.x < 256){
    int i = blockIdx.x*256 + threadIdx.x;
    float v = h0[i];
    u16 hi = f2bf(v);
    hhi[i] = hi;
    hlo[i] = f2bf(v - bf2f(hi));
  } else {
    cnt[threadIdx.x*16] = 0;
  }
}

// ---- persistent LSTM: 256 wgs = 16 batch-groups (8 rows) x 16 col-wgs (32 h-cols)
__global__ void __launch_bounds__(256, 1)
k_rnn(const int* __restrict__ x, const float* __restrict__ embed, const float* __restrict__ c0,
      const u16* __restrict__ WhT, const u16* __restrict__ WxT, const float* __restrict__ tb,
      u16* __restrict__ hhi, u16* __restrict__ hlo, float* __restrict__ hf, u32* cnt)
{
  const int bx = blockIdx.x;
  const int g = bx & 15;      // batch group: members bx ≡ g (mod 16) -> same XCD under %8 round-robin
  const int w = bx >> 4;      // h-column chunk [w*32, w*32+32)
  const int tid = threadIdx.x;
  const int v = tid >> 6;     // wave 0..3, owns N-tiles {2v, 2v+1}
  const int lane = tid & 63;
  const int l15 = lane & 15, l4 = lane >> 4;

  __shared__ float ldsD[2][16][132];
  __shared__ float ldsPad[20480];          // 80KB pad -> forces 1 wg/CU (co-residency)
  if (x[0] == -2147483647) ldsPad[tid] = 0.f;   // never true (x in [0,V)); defeats DCE

  // epilogue cell: thread owns (row er, h-col ehc); c stays in this register
  const int er = tid >> 5, ehc = tid & 31;
  const int eb = g*8 + er;
  const int ecol = w*32 + ehc;
  float c_val = c0[eb*512 + ecol];
  const float tb0 = tb[eb*2048 +    0 + w*32 + ehc];
  const float tb1 = tb[eb*2048 +  512 + w*32 + ehc];
  const float tb2 = tb[eb*2048 + 1024 + w*32 + ehc];
  const float tb3 = tb[eb*2048 + 1536 + w*32 + ehc];

  // preload all B fragments into registers (step-invariant).
  // local col cl = hc*4+q  ->  global gate col = q*512 + w*32 + hc  (q: i,f,g,o)
  short8 b2[2][16], b1[2][8];
  #pragma unroll
  for (int j = 0; j < 2; ++j){
    const int cl = (2*v + j)*16 + l15;
    const int cg = (cl & 3)*512 + w*32 + (cl >> 2);
    #pragma unroll
    for (int kt = 0; kt < 16; ++kt)
      b2[j][kt] = *(const short8*)(WhT + cg*512 + kt*32 + l4*8);
    #pragma unroll
    for (int kt = 0; kt < 8; ++kt)
      b1[j][kt] = *(const short8*)(WxT + cg*256 + kt*32 + l4*8);
  }

  const int ar = l15 & 7;        // A rows 8..15 duplicate 0..7 (D rows 8..15 unused)
  const int ab = g*8 + ar;
  const int xbase = ab*512;

  auto ld_emb = [&](int t, short8 (&a)[8]){
    const int idx = x[xbase + t];
    const float* ep = embed + (u32)idx*256 + l4*8;
    #pragma unroll
    for (int kt = 0; kt < 8; ++kt){
      float4 f0 = *(const float4*)(ep + kt*32);
      float4 f1 = *(const float4*)(ep + kt*32 + 4);
      short8 s;
      s[0]=(short)f2bf(f0.x); s[1]=(short)f2bf(f0.y); s[2]=(short)f2bf(f0.z); s[3]=(short)f2bf(f0.w);
      s[4]=(short)f2bf(f1.x); s[5]=(short)f2bf(f1.y); s[6]=(short)f2bf(f1.z); s[7]=(short)f2bf(f1.w);
      a[kt] = s;
    }
  };

  short8 a1A[8], a1B[8];
  ld_emb(0, a1A);

  auto step = [&](int t, short8 (&a1c)[8], short8 (&a1n)[8]){
    f32x4 acc0 = {0.f,0.f,0.f,0.f}, acc1 = {0.f,0.f,0.f,0.f};
    // x-embedding contribution — independent of h_t, hides inside the flag wait
    #pragma unroll
    for (int kt = 0; kt < 8; ++kt){
      acc0 = __builtin_amdgcn_mfma_f32_16x16x32_bf16(a1c[kt], b1[0][kt], acc0, 0, 0, 0);
      acc1 = __builtin_amdgcn_mfma_f32_16x16x32_bf16(a1c[kt], b1[1][kt], acc1, 0, 0, 0);
    }
    // prefetch next step's embedding rows (f32 -> bf16)
    ld_emb((t < 511) ? t + 1 : 511, a1n);
    // wait until all 16 wgs of this group have published h_t
    if (t > 0){
      const u32 tgt = (u32)t;
      bool ok;
      do {
        u32 cv = 0xFFFFFFFFu;
        if (lane < 16)
          cv = __hip_atomic_load(cnt + (((u32)lane << 4) | (u32)g)*16,
                                 __ATOMIC_RELAXED, __HIP_MEMORY_SCOPE_AGENT);
        ok = __all((int)(lane >= 16 || cv >= tgt)) != 0;
        if (!ok) __builtin_amdgcn_s_sleep(1);
      } while (!ok);
      __builtin_amdgcn_fence(__ATOMIC_ACQUIRE, "agent");
    }
    // recurrent contribution: h_t as bf16 hi+lo split (precision)
    {
      const u16* hb = hhi + (t & 1)*65536 + ab*512;
      const u16* lb = hlo + (t & 1)*65536 + ab*512;
      #pragma unroll
      for (int half = 0; half < 2; ++half){
        short8 ah[8], al[8];
        #pragma unroll
        for (int kk = 0; kk < 8; ++kk){
          const int off = (half*8 + kk)*32 + l4*8;
          ah[kk] = *(const short8*)(hb + off);
          al[kk] = *(const short8*)(lb + off);
        }
        #pragma unroll
        for (int kk = 0; kk < 8; ++kk){
          const int kt = half*8 + kk;
          acc0 = __builtin_amdgcn_mfma_f32_16x16x32_bf16(ah[kk], b2[0][kt], acc0, 0, 0, 0);
          acc0 = __builtin_amdgcn_mfma_f32_16x16x32_bf16(al[kk], b2[0][kt], acc0, 0, 0, 0);
          acc1 = __builtin_amdgcn_mfma_f32_16x16x32_bf16(ah[kk], b2[1][kt], acc1, 0, 0, 0);
          acc1 = __builtin_amdgcn_mfma_f32_16x16x32_bf16(al[kk], b2[1][kt], acc1, 0, 0, 0);
        }
      }
    }
    // D fragments -> LDS (C/D layout: col=lane&15, row=(lane>>4)*4+reg)
    const int p = t & 1;
    #pragma unroll
    for (int jj = 0; jj < 4; ++jj){
      ldsD[p][l4*4 + jj][(2*v + 0)*16 + l15] = acc0[jj];
      ldsD[p][l4*4 + jj][(2*v + 1)*16 + l15] = acc1[jj];
    }
    __syncthreads();
    // gates: local col hc*4+q holds gate q of cell (er, ehc)
    const float pre0 = ldsD[p][er][ehc*4 + 0] + tb0;
    const float pre1 = ldsD[p][er][ehc*4 + 1] + tb1;
    const float pre2 = ldsD[p][er][ehc*4 + 2] + tb2;
    const float pre3 = ldsD[p][er][ehc*4 + 3] + tb3;
    const float iv = sigf(pre0);
    const float fv = sigf(pre1);
    const float gv = tanh_f(pre2);
    const float ov = sigf(pre3);
    c_val = fv*c_val + iv*gv;
    const float hval = ov*tanh_f(c_val);
    if (t < 511){
      const u16 hi = f2bf(hval);
      const u16 lo = f2bf(hval - bf2f(hi));
      const int np_ = (t + 1) & 1;
      hhi[np_*65536 + eb*512 + ecol] = hi;
      hlo[np_*65536 + eb*512 + ecol] = lo;
    } else {
      hf[eb*512 + ecol] = hval;
    }
    __syncthreads();
    if (tid == 0 && t < 511){
      __builtin_amdgcn_fence(__ATOMIC_RELEASE, "agent");
      __hip_atomic_store(cnt + (u32)bx*16, (u32)(t + 1),
                         __ATOMIC_RELAXED, __HIP_MEMORY_SCOPE_AGENT);
    }
  };

  for (int t = 0; t < 512; t += 2){
    step(t,     a1A, a1B);
    step(t + 1, a1B, a1A);
  }
}

// ---- head: hid = h @ fc1_w^T + fc1_b   (f32)
__global__ void k_head1(const float* __restrict__ hf, const float* __restrict__ w1,
                        const float* __restrict__ b1v, float* __restrict__ hid){
  int b = blockIdx.y;
  int j = blockIdx.x*256 + threadIdx.x;
  if (j >= 500) return;
  float acc = b1v[j];
  const float* hr = hf + b*512;
  const float* wr = w1 + j*512;
  for (int k = 0; k < 512; ++k) acc += hr[k]*wr[k];
  hid[b*500 + j] = acc;
}

// ---- head: logits = hid @ fc2_w^T + fc2_b   (f32 out)
__global__ void k_head2(const float* __restrict__ hid, const float* __restrict__ w2,
                        const float* __restrict__ b2v, float* __restrict__ out){
  int o = blockIdx.x*256 + threadIdx.x;
  if (o >= 640) return;
  int b = o / 5, cls = o % 5;
  float acc = b2v[cls];
  const float* hr = hid + b*500;
  const float* wr = w2 + cls*500;
  for (int j = 0; j < 500; ++j) acc += hr[j]*wr[j];
  out[o] = acc;
}

extern "C" void kernel_launch(void* const* d_in, const int* in_sizes, int n_in,
                              void* d_out, int out_size, void* d_ws, size_t ws_size,
                              hipStream_t stream) {
  const int*   x     = (const int*)d_in[0];
  const float* topic = (const float*)d_in[1];
  const float* h0    = (const float*)d_in[2];
  const float* c0    = (const float*)d_in[3];
  const float* embed = (const float*)d_in[4];
  const float* Wx    = (const float*)d_in[5];
  const float* Wt    = (const float*)d_in[6];
  const float* Wh    = (const float*)d_in[7];
  const float* bias  = (const float*)d_in[8];
  const float* fc1w  = (const float*)d_in[9];
  const float* fc1b  = (const float*)d_in[10];
  const float* fc2w  = (const float*)d_in[11];
  const float* fc2b  = (const float*)d_in[12];

  char* ws = (char*)d_ws;              // total ~5.26 MB
  u16*   WhT = (u16*)(ws + 0);         // 2048*512*2  = 2097152
  u16*   WxT = (u16*)(ws + 2097152);   // 2048*256*2  = 1048576
  float* tb  = (float*)(ws + 3145728); // 128*2048*4  = 1048576
  u16*   hhi = (u16*)(ws + 4194304);   // 2*128*512*2 = 262144
  u16*   hlo = (u16*)(ws + 4456448);   // 262144
  float* hf  = (float*)(ws + 4718592); // 128*512*4   = 262144
  float* hid = (float*)(ws + 4980736); // 128*500*4   = 256000
  u32*   cnt = (u32*)(ws + 5236736);   // 256 * 64B   = 16384

  k_prep<<<dim3(1536), dim3(32, 8), 0, stream>>>(Wh, Wx, WhT, WxT);
  k_topic<<<dim3(8, 128), dim3(256), 0, stream>>>(topic, Wt, bias, tb);
  k_init<<<dim3(257), dim3(256), 0, stream>>>(h0, hhi, hlo, cnt);

  // plain launch; 97KB static LDS/wg forces 1 wg/CU so all 256 wgs are co-resident
  k_rnn<<<dim3(256), dim3(256), 0, stream>>>(x, embed, c0, WhT, WxT, tb, hhi, hlo, hf, cnt);

  k_head1<<<dim3(2, 128), dim3(256), 0, stream>>>(hf, fc1w, fc1b, hid);
  k_head2<<<dim3(3), dim3(256), 0, stream>>>(hid, fc2w, fc2b, (float*)d_out);
}

// Round 3
// 2433.126 us; speedup vs baseline: 3.2823x; 3.2823x over previous
//
#include <hip/hip_runtime.h>
#include <hip/hip_bf16.h>

typedef unsigned short u16;
typedef unsigned int u32;
typedef __attribute__((ext_vector_type(8))) short short8;
typedef __attribute__((ext_vector_type(4))) float f32x4;

// sizes: V=50000 E=256 H=512 T=50 C=5 B=128 S=512 FC1=500, 4H=2048
// ALL float tensors are f32 on device; x is int32; d_out is f32.

__device__ __forceinline__ float bf2f(u16 v){ union{u32 u; float f;} x; x.u = ((u32)v)<<16; return x.f; }
__device__ __forceinline__ u16 f2bf(float f){ union{float f; u32 u;} x; x.f = f; u32 r = ((x.u>>16)&1u) + 0x7FFFu; return (u16)((x.u + r)>>16); }
__device__ __forceinline__ float sigf(float x){ return 1.f/(1.f+__expf(-x)); }
__device__ __forceinline__ float tanh_f(float x){ return 2.f/(1.f+__expf(-2.f*x)) - 1.f; }

// ---- transpose+cast: W_h f32 [512][2048] -> WhT bf16 [2048][512]
//                      W_x f32 [256][2048] -> WxT bf16 [2048][256]
__global__ void k_prep(const float* __restrict__ Wh, const float* __restrict__ Wx,
                       u16* __restrict__ WhT, u16* __restrict__ WxT){
  __shared__ u16 tile[32][33];
  int b = blockIdx.x;
  const float* src; u16* dst; int K, kt, nt;
  if (b < 1024){ src = Wh; dst = WhT; K = 512; kt = b & 15; nt = b >> 4; }
  else { b -= 1024; src = Wx; dst = WxT; K = 256; kt = b & 7; nt = b >> 3; }
  int tx = threadIdx.x, ty = threadIdx.y;
  #pragma unroll
  for (int p = 0; p < 4; ++p){
    int r = p*8 + ty;
    tile[r][tx] = f2bf(src[(kt*32 + r)*2048 + nt*32 + tx]);
  }
  __syncthreads();
  #pragma unroll
  for (int p = 0; p < 4; ++p){
    int r = p*8 + ty;
    dst[(nt*32 + r)*K + kt*32 + tx] = tile[tx][r];
  }
}

// ---- tb[b][col] = bias[col] + sum_t topic[b][t]*W_t[t][col]   (all f32)
__global__ void k_topic(const float* __restrict__ topic, const float* __restrict__ Wt,
                        const float* __restrict__ bias, float* __restrict__ tb){
  int b = blockIdx.y;
  int col = blockIdx.x*256 + threadIdx.x;
  float acc = bias[col];
  #pragma unroll 5
  for (int t = 0; t < 50; ++t)
    acc += topic[b*50 + t] * Wt[t*2048 + col];
  tb[b*2048 + col] = acc;
}

// ---- init h ring buffer parity 0 (hi+lo split of f32 h0) and zero flag counters
__global__ void k_init(const float* __restrict__ h0, u16* __restrict__ hhi,
                       u16* __restrict__ hlo, u32* __restrict__ cnt){
  if (blockIdx.x < 256){
    int i = blockIdx.x*256 + threadIdx.x;
    float v = h0[i];
    u16 hi = f2bf(v);
    hhi[i] = hi;
    hlo[i] = f2bf(v - bf2f(hi));
  } else {
    cnt[threadIdx.x] = 0;   // 256 flags, group-major: flag(g,w) = cnt[g*16+w]
  }
}

// ---- persistent LSTM: 256 wgs = 16 batch-groups (8 rows) x 16 col-wgs (32 h-cols)
// Fence-free cross-wg protocol: all h traffic via sc0/sc1 (LLC-coherent) accesses,
// flags are relaxed agent atomics; release = waitcnt vmcnt(0) + syncthreads.
__global__ void __launch_bounds__(256, 1)
k_rnn(const int* __restrict__ x, const float* __restrict__ embed, const float* __restrict__ c0,
      const u16* __restrict__ WhT, const u16* __restrict__ WxT, const float* __restrict__ tb,
      u16* __restrict__ hhi, u16* __restrict__ hlo, float* __restrict__ hf, u32* cnt)
{
  const int bx = blockIdx.x;
  const int g = bx & 15;      // batch group
  const int w = bx >> 4;      // h-column chunk [w*32, w*32+32)
  const int tid = threadIdx.x;
  const int v = tid >> 6;     // wave 0..3, owns N-tiles {2v, 2v+1}
  const int lane = tid & 63;
  const int l15 = lane & 15, l4 = lane >> 4;

  __shared__ __align__(16) u16 ldsH[2][8][520];  // [hi/lo][row][col+8 pad] = 16.6KB
  __shared__ float ldsD[16][132];                // 8.4KB

  // epilogue cell: thread owns (row er, h-col ehc); c stays in this register
  const int er = tid >> 5, ehc = tid & 31;
  const int eb = g*8 + er;
  const int ecol = w*32 + ehc;
  float c_val = c0[eb*512 + ecol];
  const float tb0 = tb[eb*2048 +    0 + ecol];
  const float tb1 = tb[eb*2048 +  512 + ecol];
  const float tb2 = tb[eb*2048 + 1024 + ecol];
  const float tb3 = tb[eb*2048 + 1536 + ecol];

  // preload all B fragments into registers (step-invariant).
  // local col cl = hc*4+q  ->  global gate col = q*512 + w*32 + hc  (q: i,f,g,o)
  short8 b2[2][16], b1[2][8];
  #pragma unroll
  for (int j = 0; j < 2; ++j){
    const int cl = (2*v + j)*16 + l15;
    const int cg = (cl & 3)*512 + w*32 + (cl >> 2);
    #pragma unroll
    for (int kt = 0; kt < 16; ++kt)
      b2[j][kt] = *(const short8*)(WhT + cg*512 + kt*32 + l4*8);
    #pragma unroll
    for (int kt = 0; kt < 8; ++kt)
      b1[j][kt] = *(const short8*)(WxT + cg*256 + kt*32 + l4*8);
  }

  const int ar = l15 & 7;        // A rows 8..15 duplicate 0..7
  const int ab = g*8 + ar;
  const int xbase = ab*512;

  auto ld_emb = [&](int t, short8 (&a)[8]){
    const int idx = x[xbase + t];
    const float* ep = embed + (u32)idx*256 + l4*8;
    #pragma unroll
    for (int kt = 0; kt < 8; ++kt){
      float4 f0 = *(const float4*)(ep + kt*32);
      float4 f1 = *(const float4*)(ep + kt*32 + 4);
      short8 s;
      s[0]=(short)f2bf(f0.x); s[1]=(short)f2bf(f0.y); s[2]=(short)f2bf(f0.z); s[3]=(short)f2bf(f0.w);
      s[4]=(short)f2bf(f1.x); s[5]=(short)f2bf(f1.y); s[6]=(short)f2bf(f1.z); s[7]=(short)f2bf(f1.w);
      a[kt] = s;
    }
  };

  short8 a1A[8], a1B[8];
  ld_emb(0, a1A);

  // staging: thread stages 16 u16 per plane; row = tid>>5, cols [(tid&31)*16, +16)
  const int srow = tid >> 5;
  const int scol = (tid & 31) * 16;

  auto step = [&](int t, short8 (&a1c)[8], short8 (&a1n)[8]){
    f32x4 acc0 = {0.f,0.f,0.f,0.f}, acc1 = {0.f,0.f,0.f,0.f};
    // x-embedding contribution — independent of h_t, hides inside the flag wait
    #pragma unroll
    for (int kt = 0; kt < 8; ++kt){
      acc0 = __builtin_amdgcn_mfma_f32_16x16x32_bf16(a1c[kt], b1[0][kt], acc0, 0, 0, 0);
      acc1 = __builtin_amdgcn_mfma_f32_16x16x32_bf16(a1c[kt], b1[1][kt], acc1, 0, 0, 0);
    }
    // prefetch next step's embedding rows (normal cached loads)
    ld_emb((t < 511) ? t + 1 : 511, a1n);
    // wait until all 16 wgs of this group have published h_t (flags in ONE 64B line)
    if (t > 0){
      const u32 tgt = (u32)t;
      bool ok;
      do {
        u32 cv = 0xFFFFFFFFu;
        if (lane < 16)
          cv = __hip_atomic_load(cnt + (g*16 + lane),
                                 __ATOMIC_RELAXED, __HIP_MEMORY_SCOPE_AGENT);
        ok = __all((int)(lane >= 16 || cv >= tgt)) != 0;
      } while (!ok);
    }
    // cooperative stage of group's h (8 rows x 512, hi+lo) via LLC-coherent loads
    {
      const u16* sh = hhi + (t & 1)*65536 + g*4096 + tid*16;
      const u16* sl = hlo + (t & 1)*65536 + g*4096 + tid*16;
      f32x4 h0, h1, q0, q1;
      asm volatile("global_load_dwordx4 %0, %2, off sc0 sc1\n\t"
                   "global_load_dwordx4 %1, %3, off sc0 sc1"
                   : "=v"(h0), "=v"(h1) : "v"(sh), "v"(sh + 8));
      asm volatile("global_load_dwordx4 %0, %2, off sc0 sc1\n\t"
                   "global_load_dwordx4 %1, %3, off sc0 sc1"
                   : "=v"(q0), "=v"(q1) : "v"(sl), "v"(sl + 8));
      asm volatile("s_waitcnt vmcnt(0)" ::: "memory");
      asm volatile("" : "+v"(h0), "+v"(h1), "+v"(q0), "+v"(q1));  // pin uses after waitcnt
      *(f32x4*)&ldsH[0][srow][scol]     = h0;
      *(f32x4*)&ldsH[0][srow][scol + 8] = h1;
      *(f32x4*)&ldsH[1][srow][scol]     = q0;
      *(f32x4*)&ldsH[1][srow][scol + 8] = q1;
    }
    __syncthreads();
    // recurrent MFMAs from LDS (hi+lo split for precision)
    #pragma unroll
    for (int kt = 0; kt < 16; ++kt){
      short8 ah = *(const short8*)&ldsH[0][ar][kt*32 + l4*8];
      short8 al = *(const short8*)&ldsH[1][ar][kt*32 + l4*8];
      acc0 = __builtin_amdgcn_mfma_f32_16x16x32_bf16(ah, b2[0][kt], acc0, 0, 0, 0);
      acc0 = __builtin_amdgcn_mfma_f32_16x16x32_bf16(al, b2[0][kt], acc0, 0, 0, 0);
      acc1 = __builtin_amdgcn_mfma_f32_16x16x32_bf16(ah, b2[1][kt], acc1, 0, 0, 0);
      acc1 = __builtin_amdgcn_mfma_f32_16x16x32_bf16(al, b2[1][kt], acc1, 0, 0, 0);
    }
    // D fragments -> LDS (C/D layout: col=lane&15, row=(lane>>4)*4+reg)
    #pragma unroll
    for (int jj = 0; jj < 4; ++jj){
      ldsD[l4*4 + jj][(2*v + 0)*16 + l15] = acc0[jj];
      ldsD[l4*4 + jj][(2*v + 1)*16 + l15] = acc1[jj];
    }
    __syncthreads();
    // gates: local col hc*4+q holds gate q of cell (er, ehc)
    const float pre0 = ldsD[er][ehc*4 + 0] + tb0;
    const float pre1 = ldsD[er][ehc*4 + 1] + tb1;
    const float pre2 = ldsD[er][ehc*4 + 2] + tb2;
    const float pre3 = ldsD[er][ehc*4 + 3] + tb3;
    const float iv = sigf(pre0);
    const float fv = sigf(pre1);
    const float gv = tanh_f(pre2);
    const float ov = sigf(pre3);
    c_val = fv*c_val + iv*gv;
    const float hval = ov*tanh_f(c_val);
    if (t < 511){
      const u16 hi = f2bf(hval);
      const u16 lo = f2bf(hval - bf2f(hi));
      const int np_ = (t + 1) & 1;
      u16* dh = hhi + np_*65536 + eb*512 + ecol;
      u16* dl = hlo + np_*65536 + eb*512 + ecol;
      asm volatile("global_store_short %0, %1, off sc0 sc1" :: "v"(dh), "v"((u32)hi) : "memory");
      asm volatile("global_store_short %0, %1, off sc0 sc1" :: "v"(dl), "v"((u32)lo) : "memory");
    } else {
      hf[eb*512 + ecol] = hval;
    }
    asm volatile("s_waitcnt vmcnt(0)" ::: "memory");  // per-wave: h stores acked at LLC
    __syncthreads();                                   // all waves acked
    if (tid == 0 && t < 511){
      __hip_atomic_store(cnt + (g*16 + w), (u32)(t + 1),
                         __ATOMIC_RELAXED, __HIP_MEMORY_SCOPE_AGENT);
    }
  };

  for (int t = 0; t < 512; t += 2){
    step(t,     a1A, a1B);
    step(t + 1, a1B, a1A);
  }
}

// ---- head: hid = h @ fc1_w^T + fc1_b   (f32)
__global__ void k_head1(const float* __restrict__ hf, const float* __restrict__ w1,
                        const float* __restrict__ b1v, float* __restrict__ hid){
  int b = blockIdx.y;
  int j = blockIdx.x*256 + threadIdx.x;
  if (j >= 500) return;
  float acc = b1v[j];
  const float* hr = hf + b*512;
  const float* wr = w1 + j*512;
  for (int k = 0; k < 512; ++k) acc += hr[k]*wr[k];
  hid[b*500 + j] = acc;
}

// ---- head: logits = hid @ fc2_w^T + fc2_b   (f32 out)
__global__ void k_head2(const float* __restrict__ hid, const float* __restrict__ w2,
                        const float* __restrict__ b2v, float* __restrict__ out){
  int o = blockIdx.x*256 + threadIdx.x;
  if (o >= 640) return;
  int b = o / 5, cls = o % 5;
  float acc = b2v[cls];
  const float* hr = hid + b*500;
  const float* wr = w2 + cls*500;
  for (int j = 0; j < 500; ++j) acc += hr[j]*wr[j];
  out[o] = acc;
}

extern "C" void kernel_launch(void* const* d_in, const int* in_sizes, int n_in,
                              void* d_out, int out_size, void* d_ws, size_t ws_size,
                              hipStream_t stream) {
  const int*   x     = (const int*)d_in[0];
  const float* topic = (const float*)d_in[1];
  const float* h0    = (const float*)d_in[2];
  const float* c0    = (const float*)d_in[3];
  const float* embed = (const float*)d_in[4];
  const float* Wx    = (const float*)d_in[5];
  const float* Wt    = (const float*)d_in[6];
  const float* Wh    = (const float*)d_in[7];
  const float* bias  = (const float*)d_in[8];
  const float* fc1w  = (const float*)d_in[9];
  const float* fc1b  = (const float*)d_in[10];
  const float* fc2w  = (const float*)d_in[11];
  const float* fc2b  = (const float*)d_in[12];

  char* ws = (char*)d_ws;              // total ~5.26 MB
  u16*   WhT = (u16*)(ws + 0);         // 2048*512*2  = 2097152
  u16*   WxT = (u16*)(ws + 2097152);   // 2048*256*2  = 1048576
  float* tb  = (float*)(ws + 3145728); // 128*2048*4  = 1048576
  u16*   hhi = (u16*)(ws + 4194304);   // 2*128*512*2 = 262144
  u16*   hlo = (u16*)(ws + 4456448);   // 262144
  float* hf  = (float*)(ws + 4718592); // 128*512*4   = 262144
  float* hid = (float*)(ws + 4980736); // 128*500*4   = 256000
  u32*   cnt = (u32*)(ws + 5236736);   // 256*4 = 1KB (group-major, 64B/group)

  k_prep<<<dim3(1536), dim3(32, 8), 0, stream>>>(Wh, Wx, WhT, WxT);
  k_topic<<<dim3(8, 128), dim3(256), 0, stream>>>(topic, Wt, bias, tb);
  k_init<<<dim3(257), dim3(256), 0, stream>>>(h0, hhi, hlo, cnt);

  // 256 wgs on 256 CUs -> co-resident; flag protocol needs co-residency only, not order
  k_rnn<<<dim3(256), dim3(256), 0, stream>>>(x, embed, c0, WhT, WxT, tb, hhi, hlo, hf, cnt);

  k_head1<<<dim3(2, 128), dim3(256), 0, stream>>>(hf, fc1w, fc1b, hid);
  k_head2<<<dim3(3), dim3(256), 0, stream>>>(hid, fc2w, fc2b, (float*)d_out);
}